// Round 7
// baseline (3370.381 us; speedup 1.0000x reference)
//
#include <hip/hip_runtime.h>
#include <hip/hip_bf16.h>
#include <math.h>

#define DIMD 512
#define HEADS 8
#define NBLK 6
#define DFF 2048
#define BATCH 4
#define SEQ 2048
#define NTOK 8192   // BATCH*SEQ
#define DH 64
#define LNEPS 1e-5f
#define QSCALE 0.1803368801111204f   // 0.125 * log2(e)

typedef __bf16 bf16;
typedef __bf16 bf16x8 __attribute__((ext_vector_type(8)));
typedef __bf16 bf16x4 __attribute__((ext_vector_type(4)));
typedef float f32x4 __attribute__((ext_vector_type(4)));
typedef float f32x16 __attribute__((ext_vector_type(16)));

__device__ __forceinline__ void async16(const void* g, void* l) {
  __builtin_amdgcn_global_load_lds(
      (const __attribute__((address_space(1))) void*)g,
      (__attribute__((address_space(3))) void*)l, 16, 0, 0);
}

__device__ __forceinline__ int swz(int r) { return ((r >> 1) ^ (r >> 3)) & 3; }

// ---------------- f32 [K][N] -> bf16 [N][K] transpose (per layer) ----------------
__global__ void k_cvt_t(const float* __restrict__ in, bf16* __restrict__ out, int K, int N) {
  __shared__ float T[32][33];
  const float* src = in + (size_t)blockIdx.z * K * N;
  bf16* dst = out + (size_t)blockIdx.z * K * N;
  int k0 = blockIdx.y * 32, n0 = blockIdx.x * 32;
  int r = threadIdx.x >> 3, c4 = (threadIdx.x & 7) * 4;
  float4 v = *reinterpret_cast<const float4*>(src + (size_t)(k0 + r) * N + n0 + c4);
  T[r][c4] = v.x; T[r][c4 + 1] = v.y; T[r][c4 + 2] = v.z; T[r][c4 + 3] = v.w;
  __syncthreads();
  bf16x4 o;
  o[0] = (bf16)T[c4][r]; o[1] = (bf16)T[c4 + 1][r];
  o[2] = (bf16)T[c4 + 2][r]; o[3] = (bf16)T[c4 + 3][r];
  *reinterpret_cast<bf16x4*>(dst + (size_t)(n0 + r) * K + k0 + c4) = o;
}

// QKV variant: source col n = d*24 + which*8 + h  ->  row n' = which*512 + h*64 + d
__global__ void k_cvt_qkv(const float* __restrict__ in, bf16* __restrict__ out, int K, int N) {
  __shared__ float T[32][33];
  const float* src = in + (size_t)blockIdx.z * K * N;
  bf16* dst = out + (size_t)blockIdx.z * K * N;
  int k0 = blockIdx.y * 32, n0 = blockIdx.x * 32;
  int r = threadIdx.x >> 3, c4 = (threadIdx.x & 7) * 4;
  float4 v = *reinterpret_cast<const float4*>(src + (size_t)(k0 + r) * N + n0 + c4);
  T[r][c4] = v.x; T[r][c4 + 1] = v.y; T[r][c4 + 2] = v.z; T[r][c4 + 3] = v.w;
  __syncthreads();
  int n_src = n0 + r;
  int d = n_src / 24;
  int rem = n_src - d * 24;
  int np = (rem >> 3) * 512 + (rem & 7) * 64 + d;
  bf16x4 o;
  o[0] = (bf16)T[c4][r]; o[1] = (bf16)T[c4 + 1][r];
  o[2] = (bf16)T[c4 + 2][r]; o[3] = (bf16)T[c4 + 3][r];
  *reinterpret_cast<bf16x4*>(dst + (size_t)np * K + k0 + c4) = o;
}

// ---------------- embedding + positional encoding ----------------
__global__ void k_embed(const int* __restrict__ x, const float* __restrict__ embed,
                        const float* __restrict__ pe, bf16* __restrict__ hb,
                        float* __restrict__ hf) {
  int row = blockIdx.x;
  int t = row & (SEQ - 1);
  int tok = x[row];
  int c = threadIdx.x * 2;
  const float* e = embed + (size_t)tok * DIMD;
  const float* p = pe + (size_t)t * DIMD;
  float v0 = e[c] + p[c];
  float v1 = e[c + 1] + p[c + 1];
  size_t o = (size_t)row * DIMD + c;
  hb[o] = (bf16)v0; hb[o + 1] = (bf16)v1;
  hf[o] = v0;       hf[o + 1] = v1;
}

// ---------------- MTx128 MFMA GEMM (32x32x16), dbuf LDS, deferred async issue ----------------
enum { EPI_QKV = 0, EPI_RES = 1, EPI_GELU = 2, EPI_BIASRES = 3 };

template <int EPI, int MT>
__global__ __launch_bounds__(256) void k_gemm(
    const bf16* __restrict__ A, const bf16* __restrict__ Wt,
    const float* __restrict__ bias, const float* __restrict__ resf,
    bf16* __restrict__ out0, bf16* __restrict__ out1, bf16* __restrict__ out2,
    float* __restrict__ outf, int N, int K) {
  constexpr int TJ = (MT == 128) ? 2 : 1;
  __shared__ bf16 As[2][MT][32];
  __shared__ bf16 Bs[2][128][32];
  int tid = threadIdx.x;
  int w = tid >> 6, lane = tid & 63, hi = lane >> 5, l31 = lane & 31;
  int m0 = blockIdx.y * MT, n0 = blockIdx.x * 128;
  int wr = (MT == 128) ? (w >> 1) : 0;
  int wc = (MT == 128) ? (w & 1) : w;

  const bf16 *Ag0, *Ag1 = nullptr, *Bg0, *Bg1;
  int dA0, dA1 = 0, dB0, dB1;
  if (MT == 128) {
    int ra0 = w * 32 + (lane >> 2), ra1 = ra0 + 16;
    Ag0 = A + (size_t)(m0 + ra0) * K + ((lane & 3) ^ swz(ra0)) * 8;
    Ag1 = A + (size_t)(m0 + ra1) * K + ((lane & 3) ^ swz(ra1)) * 8;
    Bg0 = Wt + (size_t)(n0 + ra0) * K + ((lane & 3) ^ swz(ra0)) * 8;
    Bg1 = Wt + (size_t)(n0 + ra1) * K + ((lane & 3) ^ swz(ra1)) * 8;
    dA0 = w * 1024; dA1 = dA0 + 512;
    dB0 = w * 1024; dB1 = dB0 + 512;
  } else {
    int ra = w * 16 + (lane >> 2);
    Ag0 = A + (size_t)(m0 + ra) * K + ((lane & 3) ^ swz(ra)) * 8;
    int rb1 = ra + 64;
    Bg0 = Wt + (size_t)(n0 + ra) * K + ((lane & 3) ^ swz(ra)) * 8;
    Bg1 = Wt + (size_t)(n0 + rb1) * K + ((lane & 3) ^ swz(rb1)) * 8;
    dA0 = w * 512;
    dB0 = w * 512; dB1 = dB0 + 2048;
  }

  int rowA[2], fA[2], colB[2], fB[2];
#pragma unroll
  for (int i = 0; i < 2; ++i) {
    rowA[i] = ((MT == 128) ? wr * 64 : 0) + i * 32 + l31;
    fA[i] = swz(rowA[i]);
  }
#pragma unroll
  for (int j = 0; j < TJ; ++j) {
    colB[j] = ((MT == 128) ? (wc * 64 + j * 32) : (wc * 32)) + l31;
    fB[j] = swz(colB[j]);
  }

  f32x16 acc[2][TJ] = {};

  auto stage = [&](int it) {
    int buf = it & 1;
    bf16* a = &As[buf][0][0];
    bf16* b = &Bs[buf][0][0];
    int k0 = it * 32;
    async16(Ag0 + k0, a + dA0);
    if (MT == 128) async16(Ag1 + k0, a + dA1);
    async16(Bg0 + k0, b + dB0);
    async16(Bg1 + k0, b + dB1);
  };

  int nit = K / 32;
  stage(0);
  for (int it = 0; it < nit; ++it) {
    int buf = it & 1;
    __syncthreads();                    // drains tile `it` (in flight one compute phase)
    if (it + 1 < nit) stage(it + 1);    // issued after barrier -> drains at next barrier
#pragma unroll
    for (int s = 0; s < 2; ++s) {
      int lc = s * 2 + hi;
      bf16x8 af[2], bfr[TJ];
#pragma unroll
      for (int i = 0; i < 2; ++i)
        af[i] = *reinterpret_cast<const bf16x8*>(&As[buf][rowA[i]][(lc ^ fA[i]) * 8]);
#pragma unroll
      for (int j = 0; j < TJ; ++j)
        bfr[j] = *reinterpret_cast<const bf16x8*>(&Bs[buf][colB[j]][(lc ^ fB[j]) * 8]);
#pragma unroll
      for (int i = 0; i < 2; ++i)
#pragma unroll
        for (int j = 0; j < TJ; ++j)
          acc[i][j] = __builtin_amdgcn_mfma_f32_32x32x16_bf16(af[i], bfr[j], acc[i][j], 0, 0, 0);
    }
  }

  // C layout (32x32): col = lane&31, row = (reg&3) + 8*(reg>>2) + 4*(lane>>5)
#pragma unroll
  for (int j = 0; j < TJ; ++j) {
    int col = n0 + ((MT == 128) ? (wc * 64 + j * 32) : (wc * 32)) + l31;
    int qwhich = 0, qhh = 0, qdd = 0;
    float bcol = 0.f;
    if (EPI == EPI_QKV) {
      qwhich = col >> 9; qhh = (col >> 6) & 7; qdd = col & 63;
    } else if (EPI == EPI_GELU || EPI == EPI_BIASRES) {
      bcol = bias[col];
    }
#pragma unroll
    for (int i = 0; i < 2; ++i) {
#pragma unroll
      for (int reg = 0; reg < 16; ++reg) {
        int row = m0 + ((MT == 128) ? wr * 64 : 0) + i * 32 + (reg & 3) + 8 * (reg >> 2) + 4 * hi;
        float v = acc[i][j][reg];
        if (EPI == EPI_QKV) {
          int b = row >> 11;
          int t = row & (SEQ - 1);
          int bh = b * HEADS + qhh;
          if (qwhich == 0)      out0[((size_t)bh * SEQ + t) * DH + qdd] = (bf16)(v * QSCALE);
          else if (qwhich == 1) out1[((size_t)bh * SEQ + t) * DH + qdd] = (bf16)v;
          else                  out2[((size_t)bh * DH + qdd) * SEQ + t] = (bf16)v;
        } else if (EPI == EPI_RES) {
          outf[(size_t)row * N + col] = v + resf[(size_t)row * N + col];
        } else if (EPI == EPI_GELU) {
          float xv = v + bcol;
          out0[(size_t)row * N + col] = (bf16)(0.5f * xv * (1.0f + erff(xv * 0.70710678118f)));
        } else {
          outf[(size_t)row * N + col] = v + bcol + resf[(size_t)row * N + col];
        }
      }
    }
  }
}

// ---------------- flash attention: 128 q/block, prefetch distance 2, XCD-local bh ----------------
__global__ __launch_bounds__(256) void k_attn(const bf16* __restrict__ q,
                                              const bf16* __restrict__ k,
                                              const bf16* __restrict__ vt,
                                              bf16* __restrict__ out) {
  __shared__ bf16 Ks[64][64];        // [key][d], XOR-swizzled 8-elem chunks
  __shared__ bf16 Vs[64][64];        // [d][key], XOR-swizzled
  __shared__ bf16 Pw[4][2][16][72];  // per-wave, per-subtile [qrow][key]
  int tid = threadIdx.x;
  int w = tid >> 6, lane = tid & 63, quad = lane >> 4, l15 = lane & 15;
  // XCD-aware remap: all 16 q-tiles of a bh land on one XCD (f%8); 4 bh/XCD -> K/V fits 4MB L2
  int f = blockIdx.y * gridDim.x + blockIdx.x;
  int xcd = f & 7, g = f >> 3;
  int bh = xcd * 4 + (g >> 4);
  int qt = g & 15;
  const bf16* qbase = q + (size_t)bh * SEQ * DH;
  const bf16* kbase = k + (size_t)bh * SEQ * DH;
  const bf16* vbase = vt + (size_t)bh * DH * SEQ;

  bf16x8 qf[2][2];
#pragma unroll
  for (int s = 0; s < 2; ++s) {
    int qrow = qt * 128 + s * 64 + w * 16 + l15;
    qf[s][0] = *reinterpret_cast<const bf16x8*>(qbase + (size_t)qrow * DH + quad * 8);
    qf[s][1] = *reinterpret_cast<const bf16x8*>(qbase + (size_t)qrow * DH + 32 + quad * 8);
  }

  int strow = w * 16 + (lane >> 3);
  int scol = ((lane & 7) ^ (lane >> 3)) * 8;
  const bf16* kp = kbase + (size_t)strow * DH + scol;
  const bf16* vp = vbase + (size_t)strow * SEQ + scol;
  bf16* kdst = &Ks[0][0] + (size_t)w * 1024 + (size_t)lane * 8;
  bf16* vdst = &Vs[0][0] + (size_t)w * 1024 + (size_t)lane * 8;

  f32x4 Ot[2][4] = {};
  float ls[2] = {0.f, 0.f};
  int fx = (l15 & 7);

  // prefetch distance 2: two register sets
  bf16x8 pre_k[2][2], pre_v[2][2];
#pragma unroll
  for (int t = 0; t < 2; ++t) {
    pre_k[t][0] = *reinterpret_cast<const bf16x8*>(kp + (size_t)t * 64 * DH);
    pre_k[t][1] = *reinterpret_cast<const bf16x8*>(kp + (size_t)t * 64 * DH + 8 * DH);
    pre_v[t][0] = *reinterpret_cast<const bf16x8*>(vp + t * 64);
    pre_v[t][1] = *reinterpret_cast<const bf16x8*>(vp + t * 64 + (size_t)8 * SEQ);
  }

  const int nit = SEQ / 64;
  for (int it = 0; it < nit; ++it) {
    int cur = it & 1;
    __syncthreads();
    *reinterpret_cast<bf16x8*>(kdst) = pre_k[cur][0];
    *reinterpret_cast<bf16x8*>(kdst + 512) = pre_k[cur][1];
    *reinterpret_cast<bf16x8*>(vdst) = pre_v[cur][0];
    *reinterpret_cast<bf16x8*>(vdst + 512) = pre_v[cur][1];
    __syncthreads();
    if (it + 2 < nit) {
      size_t ko = (size_t)(it + 2) * 64;
      pre_k[cur][0] = *reinterpret_cast<const bf16x8*>(kp + ko * DH);
      pre_k[cur][1] = *reinterpret_cast<const bf16x8*>(kp + ko * DH + 8 * DH);
      pre_v[cur][0] = *reinterpret_cast<const bf16x8*>(vp + ko);
      pre_v[cur][1] = *reinterpret_cast<const bf16x8*>(vp + ko + (size_t)8 * SEQ);
    }

    // S^T = K(64x64) @ Q^T, both subtiles share the K-frag reads
    f32x4 st[2][4];
#pragma unroll
    for (int nt = 0; nt < 4; ++nt) {
      bf16x8 kf0 = *reinterpret_cast<const bf16x8*>(&Ks[nt * 16 + l15][(quad ^ fx) * 8]);
      bf16x8 kf1 = *reinterpret_cast<const bf16x8*>(&Ks[nt * 16 + l15][((quad + 4) ^ fx) * 8]);
#pragma unroll
      for (int s = 0; s < 2; ++s) {
        f32x4 z = {};
        z = __builtin_amdgcn_mfma_f32_16x16x32_bf16(kf0, qf[s][0], z, 0, 0, 0);
        z = __builtin_amdgcn_mfma_f32_16x16x32_bf16(kf1, qf[s][1], z, 0, 0, 0);
        st[s][nt] = z;
      }
    }

    // softmax without max-subtraction: p = exp2(s)
#pragma unroll
    for (int s = 0; s < 2; ++s)
#pragma unroll
      for (int nt = 0; nt < 4; ++nt) {
#pragma unroll
        for (int r = 0; r < 4; ++r) {
          float p = exp2f(st[s][nt][r]);
          st[s][nt][r] = p;
          ls[s] += p;
        }
        bf16x4 pv;
        pv[0] = (bf16)st[s][nt][0]; pv[1] = (bf16)st[s][nt][1];
        pv[2] = (bf16)st[s][nt][2]; pv[3] = (bf16)st[s][nt][3];
        *reinterpret_cast<bf16x4*>(&Pw[w][s][l15][nt * 16 + quad * 4]) = pv;
      }

    // O^T += V^T @ P^T, V-frag reads shared across subtiles
#pragma unroll
    for (int h = 0; h < 2; ++h) {
      bf16x8 pf0 = *reinterpret_cast<const bf16x8*>(&Pw[w][0][l15][h * 32 + quad * 8]);
      bf16x8 pf1 = *reinterpret_cast<const bf16x8*>(&Pw[w][1][l15][h * 32 + quad * 8]);
#pragma unroll
      for (int nt = 0; nt < 4; ++nt) {
        bf16x8 vf = *reinterpret_cast<const bf16x8*>(&Vs[nt * 16 + l15][((quad + 4 * h) ^ fx) * 8]);
        Ot[0][nt] = __builtin_amdgcn_mfma_f32_16x16x32_bf16(vf, pf0, Ot[0][nt], 0, 0, 0);
        Ot[1][nt] = __builtin_amdgcn_mfma_f32_16x16x32_bf16(vf, pf1, Ot[1][nt], 0, 0, 0);
      }
    }
  }

  int b = bh >> 3, hh = bh & 7;
  int qr = lane >> 2, c0 = (lane & 3) * 16;
#pragma unroll
  for (int s = 0; s < 2; ++s) {
    float l = ls[s];
    l += __shfl_xor(l, 16);
    l += __shfl_xor(l, 32);
    float inv = 1.0f / l;
#pragma unroll
    for (int nt = 0; nt < 4; ++nt) {
      bf16x4 ov;
      ov[0] = (bf16)(Ot[s][nt][0] * inv); ov[1] = (bf16)(Ot[s][nt][1] * inv);
      ov[2] = (bf16)(Ot[s][nt][2] * inv); ov[3] = (bf16)(Ot[s][nt][3] * inv);
      *reinterpret_cast<bf16x4*>(&Pw[w][s][l15][nt * 16 + quad * 4]) = ov;
    }
    bf16x8 o0 = *reinterpret_cast<const bf16x8*>(&Pw[w][s][qr][c0]);
    bf16x8 o1 = *reinterpret_cast<const bf16x8*>(&Pw[w][s][qr][c0 + 8]);
    int token = b * SEQ + qt * 128 + s * 64 + w * 16 + qr;
    *reinterpret_cast<bf16x8*>(out + (size_t)token * DIMD + hh * DH + c0) = o0;
    *reinterpret_cast<bf16x8*>(out + (size_t)token * DIMD + hh * DH + c0 + 8) = o1;
  }
}

// ---------------- layernorm: f32 in, bf16 + f32 out ----------------
__global__ void k_ln(const float* __restrict__ in, const float* __restrict__ g,
                     const float* __restrict__ b, bf16* __restrict__ outb,
                     float* __restrict__ outf) {
  int wid = (blockIdx.x * blockDim.x + threadIdx.x) >> 6;
  int lane = threadIdx.x & 63;
  const float* row = in + (size_t)wid * DIMD;
  float4 x0 = *reinterpret_cast<const float4*>(row + lane * 8);
  float4 x1 = *reinterpret_cast<const float4*>(row + lane * 8 + 4);
  float xs[8] = {x0.x, x0.y, x0.z, x0.w, x1.x, x1.y, x1.z, x1.w};
  float s = 0.f, sq = 0.f;
#pragma unroll
  for (int j = 0; j < 8; ++j) { s += xs[j]; sq += xs[j] * xs[j]; }
#pragma unroll
  for (int m = 1; m < 64; m <<= 1) { s += __shfl_xor(s, m); sq += __shfl_xor(sq, m); }
  float mu = s * (1.0f / DIMD);
  float var = sq * (1.0f / DIMD) - mu * mu;
  float rstd = rsqrtf(var + LNEPS);
  bf16x8 ov;
#pragma unroll
  for (int j = 0; j < 8; ++j) {
    int c = lane * 8 + j;
    float y = (xs[j] - mu) * rstd * g[c] + b[c];
    ov[j] = (bf16)y;
    outf[(size_t)wid * DIMD + c] = y;
  }
  *reinterpret_cast<bf16x8*>(outb + (size_t)wid * DIMD + lane * 8) = ov;
}

// ---------------- classifier head ----------------
__global__ void k_head(const bf16* __restrict__ h, const float* __restrict__ w,
                       const float* __restrict__ bh, float* __restrict__ out) {
  int row = (blockIdx.x * blockDim.x + threadIdx.x) >> 6;
  int lane = threadIdx.x & 63;
  bf16x8 xv = *reinterpret_cast<const bf16x8*>(h + (size_t)row * DIMD + lane * 8);
  float s = 0.f;
#pragma unroll
  for (int j = 0; j < 8; ++j) s += (float)xv[j] * w[lane * 8 + j];
#pragma unroll
  for (int m = 1; m < 64; m <<= 1) s += __shfl_xor(s, m);
  if (lane == 0) out[row] = s + bh[0];
}

extern "C" void kernel_launch(void* const* d_in, const int* in_sizes, int n_in,
                              void* d_out, int out_size, void* d_ws, size_t ws_size,
                              hipStream_t stream) {
  const int*   x     = (const int*)d_in[0];
  const float* embed = (const float*)d_in[1];
  const float* pe    = (const float*)d_in[2];
  const float* Wqkv  = (const float*)d_in[3];
  const float* W0    = (const float*)d_in[4];
  const float* g1    = (const float*)d_in[5];
  const float* b1    = (const float*)d_in[6];
  const float* g2    = (const float*)d_in[7];
  const float* b2    = (const float*)d_in[8];
  const float* Wl1   = (const float*)d_in[9];
  const float* bl1   = (const float*)d_in[10];
  const float* Wl2   = (const float*)d_in[11];
  const float* bl2   = (const float*)d_in[12];
  const float* Whead = (const float*)d_in[13];
  const float* bhead = (const float*)d_in[14];
  float* outp = (float*)d_out;

  char* ws = (char*)d_ws;
  size_t off = 0;
  auto alloc = [&](size_t bytes) { void* p = ws + off; off += (bytes + 255) & ~(size_t)255; return p; };
  const size_t ACT = (size_t)NTOK * DIMD;
  bf16*  hb   = (bf16*)alloc(ACT * 2);
  float* hf   = (float*)alloc(ACT * 4);
  bf16*  qb   = (bf16*)alloc(ACT * 2);
  bf16*  kb   = (bf16*)alloc(ACT * 2);
  bf16*  vtb  = (bf16*)alloc(ACT * 2);
  bf16*  ao   = (bf16*)alloc(ACT * 2);
  float* r32  = (float*)alloc(ACT * 4);
  bf16*  yb   = (bf16*)alloc(ACT * 2);
  float* yf   = (float*)alloc(ACT * 4);
  bf16*  wqkt = (bf16*)alloc((size_t)NBLK * DIMD * 3 * DIMD * 2);
  bf16*  w0t  = (bf16*)alloc((size_t)NBLK * DIMD * DIMD * 2);
  bf16*  wl1t = (bf16*)alloc((size_t)NBLK * DIMD * DFF * 2);
  bf16*  wl2t = (bf16*)alloc((size_t)NBLK * DFF * DIMD * 2);
  bf16*  mid  = qb;   // [NTOK][DFF] bf16 = 32 MB, aliases q/k/vt/ao

  k_cvt_qkv<<<dim3(3 * DIMD / 32, DIMD / 32, NBLK), 256, 0, stream>>>(Wqkv, wqkt, DIMD, 3 * DIMD);
  k_cvt_t<<<dim3(DIMD / 32, DIMD / 32, NBLK), 256, 0, stream>>>(W0, w0t, DIMD, DIMD);
  k_cvt_t<<<dim3(DFF / 32, DIMD / 32, NBLK), 256, 0, stream>>>(Wl1, wl1t, DIMD, DFF);
  k_cvt_t<<<dim3(DIMD / 32, DFF / 32, NBLK), 256, 0, stream>>>(Wl2, wl2t, DFF, DIMD);

  k_embed<<<NTOK, 256, 0, stream>>>(x, embed, pe, hb, hf);
  for (int i = 0; i < NBLK; ++i) {
    k_gemm<EPI_QKV, 128><<<dim3(3 * DIMD / 128, NTOK / 128), 256, 0, stream>>>(
        hb, wqkt + (size_t)i * DIMD * 3 * DIMD, nullptr, nullptr,
        qb, kb, vtb, nullptr, 3 * DIMD, DIMD);
    k_attn<<<dim3(SEQ / 128, BATCH * HEADS), 256, 0, stream>>>(qb, kb, vtb, ao);
    k_gemm<EPI_RES, 64><<<dim3(DIMD / 128, NTOK / 64), 256, 0, stream>>>(
        ao, w0t + (size_t)i * DIMD * DIMD, nullptr, hf,
        nullptr, nullptr, nullptr, r32, DIMD, DIMD);
    k_ln<<<NTOK / 4, 256, 0, stream>>>(r32, g1 + i * DIMD, b1 + i * DIMD, yb, yf);
    k_gemm<EPI_GELU, 128><<<dim3(DFF / 128, NTOK / 128), 256, 0, stream>>>(
        yb, wl1t + (size_t)i * DIMD * DFF, bl1 + (size_t)i * DFF, nullptr,
        mid, nullptr, nullptr, nullptr, DFF, DIMD);
    k_gemm<EPI_BIASRES, 64><<<dim3(DIMD / 128, NTOK / 64), 256, 0, stream>>>(
        mid, wl2t + (size_t)i * DFF * DIMD, bl2 + (size_t)i * DIMD, yf,
        nullptr, nullptr, nullptr, r32, DIMD, DFF);
    k_ln<<<NTOK / 4, 256, 0, stream>>>(r32, g2 + i * DIMD, b2 + i * DIMD, hb, hf);
  }
  k_head<<<NTOK / 4, 256, 0, stream>>>(hb, Whead, bhead, outp);
}

// Round 8
// 1443.110 us; speedup vs baseline: 2.3355x; 2.3355x over previous
//
#include <hip/hip_runtime.h>
#include <hip/hip_bf16.h>
#include <math.h>

#define DIMD 512
#define HEADS 8
#define NBLK 6
#define DFF 2048
#define BATCH 4
#define SEQ 2048
#define NTOK 8192   // BATCH*SEQ
#define DH 64
#define LNEPS 1e-5f
#define QSCALE 0.1803368801111204f   // 0.125 * log2(e)

typedef __bf16 bf16;
typedef __bf16 bf16x8 __attribute__((ext_vector_type(8)));
typedef __bf16 bf16x4 __attribute__((ext_vector_type(4)));
typedef float f32x4 __attribute__((ext_vector_type(4)));
typedef float f32x16 __attribute__((ext_vector_type(16)));

__device__ __forceinline__ void async16(const void* g, void* l) {
  __builtin_amdgcn_global_load_lds(
      (const __attribute__((address_space(1))) void*)g,
      (__attribute__((address_space(3))) void*)l, 16, 0, 0);
}

__device__ __forceinline__ int swz(int r) { return ((r >> 1) ^ (r >> 3)) & 3; }

// ---------------- f32 [K][N] -> bf16 [N][K] transpose (per layer) ----------------
__global__ void k_cvt_t(const float* __restrict__ in, bf16* __restrict__ out, int K, int N) {
  __shared__ float T[32][33];
  const float* src = in + (size_t)blockIdx.z * K * N;
  bf16* dst = out + (size_t)blockIdx.z * K * N;
  int k0 = blockIdx.y * 32, n0 = blockIdx.x * 32;
  int r = threadIdx.x >> 3, c4 = (threadIdx.x & 7) * 4;
  float4 v = *reinterpret_cast<const float4*>(src + (size_t)(k0 + r) * N + n0 + c4);
  T[r][c4] = v.x; T[r][c4 + 1] = v.y; T[r][c4 + 2] = v.z; T[r][c4 + 3] = v.w;
  __syncthreads();
  bf16x4 o;
  o[0] = (bf16)T[c4][r]; o[1] = (bf16)T[c4 + 1][r];
  o[2] = (bf16)T[c4 + 2][r]; o[3] = (bf16)T[c4 + 3][r];
  *reinterpret_cast<bf16x4*>(dst + (size_t)(n0 + r) * K + k0 + c4) = o;
}

// QKV variant: source col n = d*24 + which*8 + h  ->  row n' = which*512 + h*64 + d
__global__ void k_cvt_qkv(const float* __restrict__ in, bf16* __restrict__ out, int K, int N) {
  __shared__ float T[32][33];
  const float* src = in + (size_t)blockIdx.z * K * N;
  bf16* dst = out + (size_t)blockIdx.z * K * N;
  int k0 = blockIdx.y * 32, n0 = blockIdx.x * 32;
  int r = threadIdx.x >> 3, c4 = (threadIdx.x & 7) * 4;
  float4 v = *reinterpret_cast<const float4*>(src + (size_t)(k0 + r) * N + n0 + c4);
  T[r][c4] = v.x; T[r][c4 + 1] = v.y; T[r][c4 + 2] = v.z; T[r][c4 + 3] = v.w;
  __syncthreads();
  int n_src = n0 + r;
  int d = n_src / 24;
  int rem = n_src - d * 24;
  int np = (rem >> 3) * 512 + (rem & 7) * 64 + d;
  bf16x4 o;
  o[0] = (bf16)T[c4][r]; o[1] = (bf16)T[c4 + 1][r];
  o[2] = (bf16)T[c4 + 2][r]; o[3] = (bf16)T[c4 + 3][r];
  *reinterpret_cast<bf16x4*>(dst + (size_t)np * K + k0 + c4) = o;
}

// ---------------- embedding + positional encoding ----------------
__global__ void k_embed(const int* __restrict__ x, const float* __restrict__ embed,
                        const float* __restrict__ pe, bf16* __restrict__ hb,
                        float* __restrict__ hf) {
  int row = blockIdx.x;
  int t = row & (SEQ - 1);
  int tok = x[row];
  int c = threadIdx.x * 2;
  const float* e = embed + (size_t)tok * DIMD;
  const float* p = pe + (size_t)t * DIMD;
  float v0 = e[c] + p[c];
  float v1 = e[c + 1] + p[c + 1];
  size_t o = (size_t)row * DIMD + c;
  hb[o] = (bf16)v0; hb[o + 1] = (bf16)v1;
  hf[o] = v0;       hf[o + 1] = v1;
}

// ---------------- MTx128 MFMA GEMM (32x32x16), dbuf LDS, deferred async issue ----------------
enum { EPI_QKV = 0, EPI_RES = 1, EPI_GELU = 2, EPI_BIASRES = 3 };

template <int EPI, int MT>
__global__ __launch_bounds__(256) void k_gemm(
    const bf16* __restrict__ A, const bf16* __restrict__ Wt,
    const float* __restrict__ bias, const float* __restrict__ resf,
    bf16* __restrict__ out0, bf16* __restrict__ out1, bf16* __restrict__ out2,
    float* __restrict__ outf, int N, int K) {
  constexpr int TJ = (MT == 128) ? 2 : 1;
  __shared__ bf16 As[2][MT][32];
  __shared__ bf16 Bs[2][128][32];
  int tid = threadIdx.x;
  int w = tid >> 6, lane = tid & 63, hi = lane >> 5, l31 = lane & 31;
  int m0 = blockIdx.y * MT, n0 = blockIdx.x * 128;
  int wr = (MT == 128) ? (w >> 1) : 0;
  int wc = (MT == 128) ? (w & 1) : w;

  const bf16 *Ag0, *Ag1 = nullptr, *Bg0, *Bg1;
  int dA0, dA1 = 0, dB0, dB1;
  if (MT == 128) {
    int ra0 = w * 32 + (lane >> 2), ra1 = ra0 + 16;
    Ag0 = A + (size_t)(m0 + ra0) * K + ((lane & 3) ^ swz(ra0)) * 8;
    Ag1 = A + (size_t)(m0 + ra1) * K + ((lane & 3) ^ swz(ra1)) * 8;
    Bg0 = Wt + (size_t)(n0 + ra0) * K + ((lane & 3) ^ swz(ra0)) * 8;
    Bg1 = Wt + (size_t)(n0 + ra1) * K + ((lane & 3) ^ swz(ra1)) * 8;
    dA0 = w * 1024; dA1 = dA0 + 512;
    dB0 = w * 1024; dB1 = dB0 + 512;
  } else {
    int ra = w * 16 + (lane >> 2);
    Ag0 = A + (size_t)(m0 + ra) * K + ((lane & 3) ^ swz(ra)) * 8;
    int rb1 = ra + 64;
    Bg0 = Wt + (size_t)(n0 + ra) * K + ((lane & 3) ^ swz(ra)) * 8;
    Bg1 = Wt + (size_t)(n0 + rb1) * K + ((lane & 3) ^ swz(rb1)) * 8;
    dA0 = w * 512;
    dB0 = w * 512; dB1 = dB0 + 2048;
  }

  int rowA[2], fA[2], colB[2], fB[2];
#pragma unroll
  for (int i = 0; i < 2; ++i) {
    rowA[i] = ((MT == 128) ? wr * 64 : 0) + i * 32 + l31;
    fA[i] = swz(rowA[i]);
  }
#pragma unroll
  for (int j = 0; j < TJ; ++j) {
    colB[j] = ((MT == 128) ? (wc * 64 + j * 32) : (wc * 32)) + l31;
    fB[j] = swz(colB[j]);
  }

  f32x16 acc[2][TJ] = {};

  auto stage = [&](int it) {
    int buf = it & 1;
    bf16* a = &As[buf][0][0];
    bf16* b = &Bs[buf][0][0];
    int k0 = it * 32;
    async16(Ag0 + k0, a + dA0);
    if (MT == 128) async16(Ag1 + k0, a + dA1);
    async16(Bg0 + k0, b + dB0);
    async16(Bg1 + k0, b + dB1);
  };

  int nit = K / 32;
  stage(0);
  for (int it = 0; it < nit; ++it) {
    int buf = it & 1;
    __syncthreads();                    // drains tile `it` (in flight one compute phase)
    if (it + 1 < nit) stage(it + 1);    // issued after barrier -> drains at next barrier
#pragma unroll
    for (int s = 0; s < 2; ++s) {
      int lc = s * 2 + hi;
      bf16x8 af[2], bfr[TJ];
#pragma unroll
      for (int i = 0; i < 2; ++i)
        af[i] = *reinterpret_cast<const bf16x8*>(&As[buf][rowA[i]][(lc ^ fA[i]) * 8]);
#pragma unroll
      for (int j = 0; j < TJ; ++j)
        bfr[j] = *reinterpret_cast<const bf16x8*>(&Bs[buf][colB[j]][(lc ^ fB[j]) * 8]);
#pragma unroll
      for (int i = 0; i < 2; ++i)
#pragma unroll
        for (int j = 0; j < TJ; ++j)
          acc[i][j] = __builtin_amdgcn_mfma_f32_32x32x16_bf16(af[i], bfr[j], acc[i][j], 0, 0, 0);
    }
  }

  // C layout (32x32): col = lane&31, row = (reg&3) + 8*(reg>>2) + 4*(lane>>5)
#pragma unroll
  for (int j = 0; j < TJ; ++j) {
    int col = n0 + ((MT == 128) ? (wc * 64 + j * 32) : (wc * 32)) + l31;
    int qwhich = 0, qhh = 0, qdd = 0;
    float bcol = 0.f;
    if (EPI == EPI_QKV) {
      qwhich = col >> 9; qhh = (col >> 6) & 7; qdd = col & 63;
    } else if (EPI == EPI_GELU || EPI == EPI_BIASRES) {
      bcol = bias[col];
    }
#pragma unroll
    for (int i = 0; i < 2; ++i) {
#pragma unroll
      for (int reg = 0; reg < 16; ++reg) {
        int row = m0 + ((MT == 128) ? wr * 64 : 0) + i * 32 + (reg & 3) + 8 * (reg >> 2) + 4 * hi;
        float v = acc[i][j][reg];
        if (EPI == EPI_QKV) {
          int b = row >> 11;
          int t = row & (SEQ - 1);
          int bh = b * HEADS + qhh;
          if (qwhich == 0)      out0[((size_t)bh * SEQ + t) * DH + qdd] = (bf16)(v * QSCALE);
          else if (qwhich == 1) out1[((size_t)bh * SEQ + t) * DH + qdd] = (bf16)v;
          else                  out2[((size_t)bh * DH + qdd) * SEQ + t] = (bf16)v;
        } else if (EPI == EPI_RES) {
          outf[(size_t)row * N + col] = v + resf[(size_t)row * N + col];
        } else if (EPI == EPI_GELU) {
          float xv = v + bcol;
          out0[(size_t)row * N + col] = (bf16)(0.5f * xv * (1.0f + erff(xv * 0.70710678118f)));
        } else {
          outf[(size_t)row * N + col] = v + bcol + resf[(size_t)row * N + col];
        }
      }
    }
  }
}

// ---------------- flash attention: 128 q/block, dist-2 prefetch (static regs), XCD-local bh ----------------
__global__ __launch_bounds__(256) void k_attn(const bf16* __restrict__ q,
                                              const bf16* __restrict__ k,
                                              const bf16* __restrict__ vt,
                                              bf16* __restrict__ out) {
  __shared__ bf16 Ks[64][64];        // [key][d], XOR-swizzled 8-elem chunks
  __shared__ bf16 Vs[64][64];        // [d][key], XOR-swizzled
  __shared__ bf16 Pw[4][2][16][72];  // per-wave, per-subtile [qrow][key]
  int tid = threadIdx.x;
  int w = tid >> 6, lane = tid & 63, quad = lane >> 4, l15 = lane & 15;
  // XCD-aware remap: all 16 q-tiles of a bh land on one XCD (f%8); 4 bh/XCD -> K/V fits 4MB L2
  int f = blockIdx.y * gridDim.x + blockIdx.x;
  int xcd = f & 7, g = f >> 3;
  int bh = xcd * 4 + (g >> 4);
  int qt = g & 15;
  const bf16* qbase = q + (size_t)bh * SEQ * DH;
  const bf16* kbase = k + (size_t)bh * SEQ * DH;
  const bf16* vbase = vt + (size_t)bh * DH * SEQ;

  bf16x8 qf[2][2];
#pragma unroll
  for (int s = 0; s < 2; ++s) {
    int qrow = qt * 128 + s * 64 + w * 16 + l15;
    qf[s][0] = *reinterpret_cast<const bf16x8*>(qbase + (size_t)qrow * DH + quad * 8);
    qf[s][1] = *reinterpret_cast<const bf16x8*>(qbase + (size_t)qrow * DH + 32 + quad * 8);
  }

  int strow = w * 16 + (lane >> 3);
  int scol = ((lane & 7) ^ (lane >> 3)) * 8;
  const bf16* kp = kbase + (size_t)strow * DH + scol;
  const bf16* vp = vbase + (size_t)strow * SEQ + scol;
  bf16* kdst = &Ks[0][0] + (size_t)w * 1024 + (size_t)lane * 8;
  bf16* vdst = &Vs[0][0] + (size_t)w * 1024 + (size_t)lane * 8;

  f32x4 Ot[2][4] = {};
  float ls[2] = {0.f, 0.f};
  int fx = (l15 & 7);

  // prefetch distance 2: two STATIC register sets (no runtime indexing -> no scratch)
  bf16x8 ka0 = *reinterpret_cast<const bf16x8*>(kp);
  bf16x8 kb0 = *reinterpret_cast<const bf16x8*>(kp + (size_t)8 * DH);
  bf16x8 va0 = *reinterpret_cast<const bf16x8*>(vp);
  bf16x8 vb0 = *reinterpret_cast<const bf16x8*>(vp + (size_t)8 * SEQ);
  bf16x8 ka1 = *reinterpret_cast<const bf16x8*>(kp + (size_t)64 * DH);
  bf16x8 kb1 = *reinterpret_cast<const bf16x8*>(kp + (size_t)72 * DH);
  bf16x8 va1 = *reinterpret_cast<const bf16x8*>(vp + 64);
  bf16x8 vb1 = *reinterpret_cast<const bf16x8*>(vp + 64 + (size_t)8 * SEQ);

  const int nit = SEQ / 64;
  auto body = [&](int it, bf16x8& ka, bf16x8& kb, bf16x8& va, bf16x8& vb) {
    __syncthreads();
    *reinterpret_cast<bf16x8*>(kdst) = ka;
    *reinterpret_cast<bf16x8*>(kdst + 512) = kb;
    *reinterpret_cast<bf16x8*>(vdst) = va;
    *reinterpret_cast<bf16x8*>(vdst + 512) = vb;
    __syncthreads();
    if (it + 2 < nit) {   // prefetch tile it+2 into the same register set
      size_t ko = (size_t)(it + 2) * 64;
      ka = *reinterpret_cast<const bf16x8*>(kp + ko * DH);
      kb = *reinterpret_cast<const bf16x8*>(kp + ko * DH + 8 * DH);
      va = *reinterpret_cast<const bf16x8*>(vp + ko);
      vb = *reinterpret_cast<const bf16x8*>(vp + ko + (size_t)8 * SEQ);
    }

    // S^T = K(64x64) @ Q^T, both subtiles share the K-frag reads
    f32x4 st[2][4];
#pragma unroll
    for (int nt = 0; nt < 4; ++nt) {
      bf16x8 kf0 = *reinterpret_cast<const bf16x8*>(&Ks[nt * 16 + l15][(quad ^ fx) * 8]);
      bf16x8 kf1 = *reinterpret_cast<const bf16x8*>(&Ks[nt * 16 + l15][((quad + 4) ^ fx) * 8]);
#pragma unroll
      for (int s = 0; s < 2; ++s) {
        f32x4 z = {};
        z = __builtin_amdgcn_mfma_f32_16x16x32_bf16(kf0, qf[s][0], z, 0, 0, 0);
        z = __builtin_amdgcn_mfma_f32_16x16x32_bf16(kf1, qf[s][1], z, 0, 0, 0);
        st[s][nt] = z;
      }
    }

    // softmax without max-subtraction: p = exp2(s)
#pragma unroll
    for (int s = 0; s < 2; ++s)
#pragma unroll
      for (int nt = 0; nt < 4; ++nt) {
#pragma unroll
        for (int r = 0; r < 4; ++r) {
          float p = exp2f(st[s][nt][r]);
          st[s][nt][r] = p;
          ls[s] += p;
        }
        bf16x4 pv;
        pv[0] = (bf16)st[s][nt][0]; pv[1] = (bf16)st[s][nt][1];
        pv[2] = (bf16)st[s][nt][2]; pv[3] = (bf16)st[s][nt][3];
        *reinterpret_cast<bf16x4*>(&Pw[w][s][l15][nt * 16 + quad * 4]) = pv;
      }

    // O^T += V^T @ P^T, V-frag reads shared across subtiles
#pragma unroll
    for (int h = 0; h < 2; ++h) {
      bf16x8 pf0 = *reinterpret_cast<const bf16x8*>(&Pw[w][0][l15][h * 32 + quad * 8]);
      bf16x8 pf1 = *reinterpret_cast<const bf16x8*>(&Pw[w][1][l15][h * 32 + quad * 8]);
#pragma unroll
      for (int nt = 0; nt < 4; ++nt) {
        bf16x8 vf = *reinterpret_cast<const bf16x8*>(&Vs[nt * 16 + l15][((quad + 4 * h) ^ fx) * 8]);
        Ot[0][nt] = __builtin_amdgcn_mfma_f32_16x16x32_bf16(vf, pf0, Ot[0][nt], 0, 0, 0);
        Ot[1][nt] = __builtin_amdgcn_mfma_f32_16x16x32_bf16(vf, pf1, Ot[1][nt], 0, 0, 0);
      }
    }
  };

  for (int it = 0; it < nit; it += 2) {
    body(it, ka0, kb0, va0, vb0);
    body(it + 1, ka1, kb1, va1, vb1);
  }

  int b = bh >> 3, hh = bh & 7;
  int qr = lane >> 2, c0 = (lane & 3) * 16;
#pragma unroll
  for (int s = 0; s < 2; ++s) {
    float l = ls[s];
    l += __shfl_xor(l, 16);
    l += __shfl_xor(l, 32);
    float inv = 1.0f / l;
#pragma unroll
    for (int nt = 0; nt < 4; ++nt) {
      bf16x4 ov;
      ov[0] = (bf16)(Ot[s][nt][0] * inv); ov[1] = (bf16)(Ot[s][nt][1] * inv);
      ov[2] = (bf16)(Ot[s][nt][2] * inv); ov[3] = (bf16)(Ot[s][nt][3] * inv);
      *reinterpret_cast<bf16x4*>(&Pw[w][s][l15][nt * 16 + quad * 4]) = ov;
    }
    bf16x8 o0 = *reinterpret_cast<const bf16x8*>(&Pw[w][s][qr][c0]);
    bf16x8 o1 = *reinterpret_cast<const bf16x8*>(&Pw[w][s][qr][c0 + 8]);
    int token = b * SEQ + qt * 128 + s * 64 + w * 16 + qr;
    *reinterpret_cast<bf16x8*>(out + (size_t)token * DIMD + hh * DH + c0) = o0;
    *reinterpret_cast<bf16x8*>(out + (size_t)token * DIMD + hh * DH + c0 + 8) = o1;
  }
}

// ---------------- layernorm: f32 in, bf16 + f32 out ----------------
__global__ void k_ln(const float* __restrict__ in, const float* __restrict__ g,
                     const float* __restrict__ b, bf16* __restrict__ outb,
                     float* __restrict__ outf) {
  int wid = (blockIdx.x * blockDim.x + threadIdx.x) >> 6;
  int lane = threadIdx.x & 63;
  const float* row = in + (size_t)wid * DIMD;
  float4 x0 = *reinterpret_cast<const float4*>(row + lane * 8);
  float4 x1 = *reinterpret_cast<const float4*>(row + lane * 8 + 4);
  float xs[8] = {x0.x, x0.y, x0.z, x0.w, x1.x, x1.y, x1.z, x1.w};
  float s = 0.f, sq = 0.f;
#pragma unroll
  for (int j = 0; j < 8; ++j) { s += xs[j]; sq += xs[j] * xs[j]; }
#pragma unroll
  for (int m = 1; m < 64; m <<= 1) { s += __shfl_xor(s, m); sq += __shfl_xor(sq, m); }
  float mu = s * (1.0f / DIMD);
  float var = sq * (1.0f / DIMD) - mu * mu;
  float rstd = rsqrtf(var + LNEPS);
  bf16x8 ov;
#pragma unroll
  for (int j = 0; j < 8; ++j) {
    int c = lane * 8 + j;
    float y = (xs[j] - mu) * rstd * g[c] + b[c];
    ov[j] = (bf16)y;
    outf[(size_t)wid * DIMD + c] = y;
  }
  *reinterpret_cast<bf16x8*>(outb + (size_t)wid * DIMD + lane * 8) = ov;
}

// ---------------- classifier head ----------------
__global__ void k_head(const bf16* __restrict__ h, const float* __restrict__ w,
                       const float* __restrict__ bh, float* __restrict__ out) {
  int row = (blockIdx.x * blockDim.x + threadIdx.x) >> 6;
  int lane = threadIdx.x & 63;
  bf16x8 xv = *reinterpret_cast<const bf16x8*>(h + (size_t)row * DIMD + lane * 8);
  float s = 0.f;
#pragma unroll
  for (int j = 0; j < 8; ++j) s += (float)xv[j] * w[lane * 8 + j];
#pragma unroll
  for (int m = 1; m < 64; m <<= 1) s += __shfl_xor(s, m);
  if (lane == 0) out[row] = s + bh[0];
}

extern "C" void kernel_launch(void* const* d_in, const int* in_sizes, int n_in,
                              void* d_out, int out_size, void* d_ws, size_t ws_size,
                              hipStream_t stream) {
  const int*   x     = (const int*)d_in[0];
  const float* embed = (const float*)d_in[1];
  const float* pe    = (const float*)d_in[2];
  const float* Wqkv  = (const float*)d_in[3];
  const float* W0    = (const float*)d_in[4];
  const float* g1    = (const float*)d_in[5];
  const float* b1    = (const float*)d_in[6];
  const float* g2    = (const float*)d_in[7];
  const float* b2    = (const float*)d_in[8];
  const float* Wl1   = (const float*)d_in[9];
  const float* bl1   = (const float*)d_in[10];
  const float* Wl2   = (const float*)d_in[11];
  const float* bl2   = (const float*)d_in[12];
  const float* Whead = (const float*)d_in[13];
  const float* bhead = (const float*)d_in[14];
  float* outp = (float*)d_out;

  char* ws = (char*)d_ws;
  size_t off = 0;
  auto alloc = [&](size_t bytes) { void* p = ws + off; off += (bytes + 255) & ~(size_t)255; return p; };
  const size_t ACT = (size_t)NTOK * DIMD;
  bf16*  hb   = (bf16*)alloc(ACT * 2);
  float* hf   = (float*)alloc(ACT * 4);
  bf16*  qb   = (bf16*)alloc(ACT * 2);
  bf16*  kb   = (bf16*)alloc(ACT * 2);
  bf16*  vtb  = (bf16*)alloc(ACT * 2);
  bf16*  ao   = (bf16*)alloc(ACT * 2);
  float* r32  = (float*)alloc(ACT * 4);
  bf16*  yb   = (bf16*)alloc(ACT * 2);
  float* yf   = (float*)alloc(ACT * 4);
  bf16*  wqkt = (bf16*)alloc((size_t)NBLK * DIMD * 3 * DIMD * 2);
  bf16*  w0t  = (bf16*)alloc((size_t)NBLK * DIMD * DIMD * 2);
  bf16*  wl1t = (bf16*)alloc((size_t)NBLK * DIMD * DFF * 2);
  bf16*  wl2t = (bf16*)alloc((size_t)NBLK * DFF * DIMD * 2);
  bf16*  mid  = qb;   // [NTOK][DFF] bf16 = 32 MB, aliases q/k/vt/ao

  k_cvt_qkv<<<dim3(3 * DIMD / 32, DIMD / 32, NBLK), 256, 0, stream>>>(Wqkv, wqkt, DIMD, 3 * DIMD);
  k_cvt_t<<<dim3(DIMD / 32, DIMD / 32, NBLK), 256, 0, stream>>>(W0, w0t, DIMD, DIMD);
  k_cvt_t<<<dim3(DFF / 32, DIMD / 32, NBLK), 256, 0, stream>>>(Wl1, wl1t, DIMD, DFF);
  k_cvt_t<<<dim3(DIMD / 32, DFF / 32, NBLK), 256, 0, stream>>>(Wl2, wl2t, DFF, DIMD);

  k_embed<<<NTOK, 256, 0, stream>>>(x, embed, pe, hb, hf);
  for (int i = 0; i < NBLK; ++i) {
    k_gemm<EPI_QKV, 128><<<dim3(3 * DIMD / 128, NTOK / 128), 256, 0, stream>>>(
        hb, wqkt + (size_t)i * DIMD * 3 * DIMD, nullptr, nullptr,
        qb, kb, vtb, nullptr, 3 * DIMD, DIMD);
    k_attn<<<dim3(SEQ / 128, BATCH * HEADS), 256, 0, stream>>>(qb, kb, vtb, ao);
    k_gemm<EPI_RES, 64><<<dim3(DIMD / 128, NTOK / 64), 256, 0, stream>>>(
        ao, w0t + (size_t)i * DIMD * DIMD, nullptr, hf,
        nullptr, nullptr, nullptr, r32, DIMD, DIMD);
    k_ln<<<NTOK / 4, 256, 0, stream>>>(r32, g1 + i * DIMD, b1 + i * DIMD, yb, yf);
    k_gemm<EPI_GELU, 128><<<dim3(DFF / 128, NTOK / 128), 256, 0, stream>>>(
        yb, wl1t + (size_t)i * DIMD * DFF, bl1 + (size_t)i * DFF, nullptr,
        mid, nullptr, nullptr, nullptr, DFF, DIMD);
    k_gemm<EPI_BIASRES, 64><<<dim3(DIMD / 128, NTOK / 64), 256, 0, stream>>>(
        mid, wl2t + (size_t)i * DFF * DIMD, bl2 + (size_t)i * DIMD, yf,
        nullptr, nullptr, nullptr, r32, DIMD, DFF);
    k_ln<<<NTOK / 4, 256, 0, stream>>>(r32, g2 + i * DIMD, b2 + i * DIMD, hb, hf);
  }
  k_head<<<NTOK / 4, 256, 0, stream>>>(hb, Whead, bhead, outp);
}

// Round 9
// 1319.487 us; speedup vs baseline: 2.5543x; 1.0937x over previous
//
#include <hip/hip_runtime.h>
#include <hip/hip_bf16.h>
#include <math.h>

#define DIMD 512
#define HEADS 8
#define NBLK 6
#define DFF 2048
#define BATCH 4
#define SEQ 2048
#define NTOK 8192   // BATCH*SEQ
#define DH 64
#define LNEPS 1e-5f
#define QSCALE 0.1803368801111204f   // 0.125 * log2(e)

typedef __bf16 bf16;
typedef __bf16 bf16x8 __attribute__((ext_vector_type(8)));
typedef __bf16 bf16x4 __attribute__((ext_vector_type(4)));
typedef float f32x4 __attribute__((ext_vector_type(4)));
typedef float f32x16 __attribute__((ext_vector_type(16)));

__device__ __forceinline__ void async16(const void* g, void* l) {
  __builtin_amdgcn_global_load_lds(
      (const __attribute__((address_space(1))) void*)g,
      (__attribute__((address_space(3))) void*)l, 16, 0, 0);
}

__device__ __forceinline__ int swz(int r) { return ((r >> 1) ^ (r >> 3)) & 3; }

// ---------------- f32 [K][N] -> bf16 [N][K] transpose (per layer) ----------------
__global__ void k_cvt_t(const float* __restrict__ in, bf16* __restrict__ out, int K, int N) {
  __shared__ float T[32][33];
  const float* src = in + (size_t)blockIdx.z * K * N;
  bf16* dst = out + (size_t)blockIdx.z * K * N;
  int k0 = blockIdx.y * 32, n0 = blockIdx.x * 32;
  int r = threadIdx.x >> 3, c4 = (threadIdx.x & 7) * 4;
  float4 v = *reinterpret_cast<const float4*>(src + (size_t)(k0 + r) * N + n0 + c4);
  T[r][c4] = v.x; T[r][c4 + 1] = v.y; T[r][c4 + 2] = v.z; T[r][c4 + 3] = v.w;
  __syncthreads();
  bf16x4 o;
  o[0] = (bf16)T[c4][r]; o[1] = (bf16)T[c4 + 1][r];
  o[2] = (bf16)T[c4 + 2][r]; o[3] = (bf16)T[c4 + 3][r];
  *reinterpret_cast<bf16x4*>(dst + (size_t)(n0 + r) * K + k0 + c4) = o;
}

// QKV variant: source col n = d*24 + which*8 + h  ->  row n' = which*512 + h*64 + d
__global__ void k_cvt_qkv(const float* __restrict__ in, bf16* __restrict__ out, int K, int N) {
  __shared__ float T[32][33];
  const float* src = in + (size_t)blockIdx.z * K * N;
  bf16* dst = out + (size_t)blockIdx.z * K * N;
  int k0 = blockIdx.y * 32, n0 = blockIdx.x * 32;
  int r = threadIdx.x >> 3, c4 = (threadIdx.x & 7) * 4;
  float4 v = *reinterpret_cast<const float4*>(src + (size_t)(k0 + r) * N + n0 + c4);
  T[r][c4] = v.x; T[r][c4 + 1] = v.y; T[r][c4 + 2] = v.z; T[r][c4 + 3] = v.w;
  __syncthreads();
  int n_src = n0 + r;
  int d = n_src / 24;
  int rem = n_src - d * 24;
  int np = (rem >> 3) * 512 + (rem & 7) * 64 + d;
  bf16x4 o;
  o[0] = (bf16)T[c4][r]; o[1] = (bf16)T[c4 + 1][r];
  o[2] = (bf16)T[c4 + 2][r]; o[3] = (bf16)T[c4 + 3][r];
  *reinterpret_cast<bf16x4*>(dst + (size_t)np * K + k0 + c4) = o;
}

// ---------------- embedding + positional encoding (bf16 out) ----------------
__global__ void k_embed(const int* __restrict__ x, const float* __restrict__ embed,
                        const float* __restrict__ pe, bf16* __restrict__ hb) {
  int row = blockIdx.x;
  int t = row & (SEQ - 1);
  int tok = x[row];
  int c = threadIdx.x * 2;
  const float* e = embed + (size_t)tok * DIMD;
  const float* p = pe + (size_t)t * DIMD;
  size_t o = (size_t)row * DIMD + c;
  hb[o] = (bf16)(e[c] + p[c]);
  hb[o + 1] = (bf16)(e[c + 1] + p[c + 1]);
}

// ---------------- MTx128 MFMA GEMM (32x32x16), single-buf 2-barrier staging ----------------
enum { EPI_QKV = 0, EPI_RES = 1, EPI_GELU = 2, EPI_BIASRES = 3 };

template <int EPI, int MT>
__global__ __launch_bounds__(256) void k_gemm(
    const bf16* __restrict__ A, const bf16* __restrict__ Wt,
    const float* __restrict__ bias, const bf16* __restrict__ resb,
    bf16* __restrict__ out0, bf16* __restrict__ out1, bf16* __restrict__ out2,
    int N, int K) {
  constexpr int TJ = (MT == 128) ? 2 : 1;
  __shared__ bf16 As[MT][32];
  __shared__ bf16 Bs[128][32];
  int tid = threadIdx.x;
  int w = tid >> 6, lane = tid & 63, hi = lane >> 5, l31 = lane & 31;
  int m0 = blockIdx.y * MT, n0 = blockIdx.x * 128;
  int wr = (MT == 128) ? (w >> 1) : 0;
  int wc = (MT == 128) ? (w & 1) : w;

  const bf16 *Ag0, *Ag1 = nullptr, *Bg0, *Bg1;
  bf16 *dA0, *dA1 = nullptr, *dB0, *dB1;
  if (MT == 128) {
    int ra0 = w * 32 + (lane >> 2), ra1 = ra0 + 16;
    Ag0 = A + (size_t)(m0 + ra0) * K + ((lane & 3) ^ swz(ra0)) * 8;
    Ag1 = A + (size_t)(m0 + ra1) * K + ((lane & 3) ^ swz(ra1)) * 8;
    Bg0 = Wt + (size_t)(n0 + ra0) * K + ((lane & 3) ^ swz(ra0)) * 8;
    Bg1 = Wt + (size_t)(n0 + ra1) * K + ((lane & 3) ^ swz(ra1)) * 8;
    dA0 = &As[0][0] + w * 1024; dA1 = dA0 + 512;
    dB0 = &Bs[0][0] + w * 1024; dB1 = dB0 + 512;
  } else {
    int ra = w * 16 + (lane >> 2);
    Ag0 = A + (size_t)(m0 + ra) * K + ((lane & 3) ^ swz(ra)) * 8;
    int rb1 = ra + 64;
    Bg0 = Wt + (size_t)(n0 + ra) * K + ((lane & 3) ^ swz(ra)) * 8;
    Bg1 = Wt + (size_t)(n0 + rb1) * K + ((lane & 3) ^ swz(rb1)) * 8;
    dA0 = &As[0][0] + w * 512;
    dB0 = &Bs[0][0] + w * 512; dB1 = dB0 + 2048;
  }

  int rowA[2], fA[2], colB[2], fB[2];
#pragma unroll
  for (int i = 0; i < 2; ++i) {
    rowA[i] = ((MT == 128) ? wr * 64 : 0) + i * 32 + l31;
    fA[i] = swz(rowA[i]);
  }
#pragma unroll
  for (int j = 0; j < TJ; ++j) {
    colB[j] = ((MT == 128) ? (wc * 64 + j * 32) : (wc * 32)) + l31;
    fB[j] = swz(colB[j]);
  }

  f32x16 acc[2][TJ] = {};

  for (int k0 = 0; k0 < K; k0 += 32) {
    async16(Ag0 + k0, dA0);
    if (MT == 128) async16(Ag1 + k0, dA1);
    async16(Bg0 + k0, dB0);
    async16(Bg1 + k0, dB1);
    __syncthreads();

#pragma unroll
    for (int s = 0; s < 2; ++s) {
      int lc = s * 2 + hi;
      bf16x8 af[2], bfr[TJ];
#pragma unroll
      for (int i = 0; i < 2; ++i)
        af[i] = *reinterpret_cast<const bf16x8*>(&As[rowA[i]][(lc ^ fA[i]) * 8]);
#pragma unroll
      for (int j = 0; j < TJ; ++j)
        bfr[j] = *reinterpret_cast<const bf16x8*>(&Bs[colB[j]][(lc ^ fB[j]) * 8]);
#pragma unroll
      for (int i = 0; i < 2; ++i)
#pragma unroll
        for (int j = 0; j < TJ; ++j)
          acc[i][j] = __builtin_amdgcn_mfma_f32_32x32x16_bf16(af[i], bfr[j], acc[i][j], 0, 0, 0);
    }
    __syncthreads();
  }

  // C layout (32x32): col = lane&31, row = (reg&3) + 8*(reg>>2) + 4*(lane>>5)
#pragma unroll
  for (int j = 0; j < TJ; ++j) {
    int col = n0 + ((MT == 128) ? (wc * 64 + j * 32) : (wc * 32)) + l31;
    int qwhich = 0, qhh = 0, qdd = 0;
    float bcol = 0.f;
    if (EPI == EPI_QKV) {
      qwhich = col >> 9; qhh = (col >> 6) & 7; qdd = col & 63;
    } else if (EPI == EPI_GELU || EPI == EPI_BIASRES) {
      bcol = bias[col];
    }
#pragma unroll
    for (int i = 0; i < 2; ++i) {
#pragma unroll
      for (int reg = 0; reg < 16; ++reg) {
        int row = m0 + ((MT == 128) ? wr * 64 : 0) + i * 32 + (reg & 3) + 8 * (reg >> 2) + 4 * hi;
        float v = acc[i][j][reg];
        if (EPI == EPI_QKV) {
          int b = row >> 11;
          int t = row & (SEQ - 1);
          int bh = b * HEADS + qhh;
          if (qwhich == 0)      out0[((size_t)bh * SEQ + t) * DH + qdd] = (bf16)(v * QSCALE);
          else if (qwhich == 1) out1[((size_t)bh * SEQ + t) * DH + qdd] = (bf16)v;
          else                  out2[((size_t)bh * DH + qdd) * SEQ + t] = (bf16)v;
        } else if (EPI == EPI_RES) {
          out0[(size_t)row * N + col] = (bf16)(v + (float)resb[(size_t)row * N + col]);
        } else if (EPI == EPI_GELU) {
          float xv = v + bcol;
          out0[(size_t)row * N + col] = (bf16)(0.5f * xv * (1.0f + erff(xv * 0.70710678118f)));
        } else {
          out0[(size_t)row * N + col] = (bf16)(v + bcol + (float)resb[(size_t)row * N + col]);
        }
      }
    }
  }
}

// ---------------- flash attention: 128 q/block, dist-2 prefetch (static regs), XCD-local bh ----------------
__global__ __launch_bounds__(256) void k_attn(const bf16* __restrict__ q,
                                              const bf16* __restrict__ k,
                                              const bf16* __restrict__ vt,
                                              bf16* __restrict__ out) {
  __shared__ bf16 Ks[64][64];        // [key][d], XOR-swizzled 8-elem chunks
  __shared__ bf16 Vs[64][64];        // [d][key], XOR-swizzled
  __shared__ bf16 Pw[4][2][16][72];  // per-wave, per-subtile [qrow][key]
  int tid = threadIdx.x;
  int w = tid >> 6, lane = tid & 63, quad = lane >> 4, l15 = lane & 15;
  int f = blockIdx.y * gridDim.x + blockIdx.x;
  int xcd = f & 7, g = f >> 3;
  int bh = xcd * 4 + (g >> 4);
  int qt = g & 15;
  const bf16* qbase = q + (size_t)bh * SEQ * DH;
  const bf16* kbase = k + (size_t)bh * SEQ * DH;
  const bf16* vbase = vt + (size_t)bh * DH * SEQ;

  bf16x8 qf[2][2];
#pragma unroll
  for (int s = 0; s < 2; ++s) {
    int qrow = qt * 128 + s * 64 + w * 16 + l15;
    qf[s][0] = *reinterpret_cast<const bf16x8*>(qbase + (size_t)qrow * DH + quad * 8);
    qf[s][1] = *reinterpret_cast<const bf16x8*>(qbase + (size_t)qrow * DH + 32 + quad * 8);
  }

  int strow = w * 16 + (lane >> 3);
  int scol = ((lane & 7) ^ (lane >> 3)) * 8;
  const bf16* kp = kbase + (size_t)strow * DH + scol;
  const bf16* vp = vbase + (size_t)strow * SEQ + scol;
  bf16* kdst = &Ks[0][0] + (size_t)w * 1024 + (size_t)lane * 8;
  bf16* vdst = &Vs[0][0] + (size_t)w * 1024 + (size_t)lane * 8;

  f32x4 Ot[2][4] = {};
  float ls[2] = {0.f, 0.f};
  int fx = (l15 & 7);

  bf16x8 ka0 = *reinterpret_cast<const bf16x8*>(kp);
  bf16x8 kb0 = *reinterpret_cast<const bf16x8*>(kp + (size_t)8 * DH);
  bf16x8 va0 = *reinterpret_cast<const bf16x8*>(vp);
  bf16x8 vb0 = *reinterpret_cast<const bf16x8*>(vp + (size_t)8 * SEQ);
  bf16x8 ka1 = *reinterpret_cast<const bf16x8*>(kp + (size_t)64 * DH);
  bf16x8 kb1 = *reinterpret_cast<const bf16x8*>(kp + (size_t)72 * DH);
  bf16x8 va1 = *reinterpret_cast<const bf16x8*>(vp + 64);
  bf16x8 vb1 = *reinterpret_cast<const bf16x8*>(vp + 64 + (size_t)8 * SEQ);

  const int nit = SEQ / 64;
  auto body = [&](int it, bf16x8& ka, bf16x8& kb, bf16x8& va, bf16x8& vb) {
    __syncthreads();
    *reinterpret_cast<bf16x8*>(kdst) = ka;
    *reinterpret_cast<bf16x8*>(kdst + 512) = kb;
    *reinterpret_cast<bf16x8*>(vdst) = va;
    *reinterpret_cast<bf16x8*>(vdst + 512) = vb;
    __syncthreads();
    if (it + 2 < nit) {
      size_t ko = (size_t)(it + 2) * 64;
      ka = *reinterpret_cast<const bf16x8*>(kp + ko * DH);
      kb = *reinterpret_cast<const bf16x8*>(kp + ko * DH + 8 * DH);
      va = *reinterpret_cast<const bf16x8*>(vp + ko);
      vb = *reinterpret_cast<const bf16x8*>(vp + ko + (size_t)8 * SEQ);
    }

    f32x4 st[2][4];
#pragma unroll
    for (int nt = 0; nt < 4; ++nt) {
      bf16x8 kf0 = *reinterpret_cast<const bf16x8*>(&Ks[nt * 16 + l15][(quad ^ fx) * 8]);
      bf16x8 kf1 = *reinterpret_cast<const bf16x8*>(&Ks[nt * 16 + l15][((quad + 4) ^ fx) * 8]);
#pragma unroll
      for (int s = 0; s < 2; ++s) {
        f32x4 z = {};
        z = __builtin_amdgcn_mfma_f32_16x16x32_bf16(kf0, qf[s][0], z, 0, 0, 0);
        z = __builtin_amdgcn_mfma_f32_16x16x32_bf16(kf1, qf[s][1], z, 0, 0, 0);
        st[s][nt] = z;
      }
    }

#pragma unroll
    for (int s = 0; s < 2; ++s)
#pragma unroll
      for (int nt = 0; nt < 4; ++nt) {
#pragma unroll
        for (int r = 0; r < 4; ++r) {
          float p = exp2f(st[s][nt][r]);
          st[s][nt][r] = p;
          ls[s] += p;
        }
        bf16x4 pv;
        pv[0] = (bf16)st[s][nt][0]; pv[1] = (bf16)st[s][nt][1];
        pv[2] = (bf16)st[s][nt][2]; pv[3] = (bf16)st[s][nt][3];
        *reinterpret_cast<bf16x4*>(&Pw[w][s][l15][nt * 16 + quad * 4]) = pv;
      }

#pragma unroll
    for (int h = 0; h < 2; ++h) {
      bf16x8 pf0 = *reinterpret_cast<const bf16x8*>(&Pw[w][0][l15][h * 32 + quad * 8]);
      bf16x8 pf1 = *reinterpret_cast<const bf16x8*>(&Pw[w][1][l15][h * 32 + quad * 8]);
#pragma unroll
      for (int nt = 0; nt < 4; ++nt) {
        bf16x8 vf = *reinterpret_cast<const bf16x8*>(&Vs[nt * 16 + l15][((quad + 4 * h) ^ fx) * 8]);
        Ot[0][nt] = __builtin_amdgcn_mfma_f32_16x16x32_bf16(vf, pf0, Ot[0][nt], 0, 0, 0);
        Ot[1][nt] = __builtin_amdgcn_mfma_f32_16x16x32_bf16(vf, pf1, Ot[1][nt], 0, 0, 0);
      }
    }
  };

  for (int it = 0; it < nit; it += 2) {
    body(it, ka0, kb0, va0, vb0);
    body(it + 1, ka1, kb1, va1, vb1);
  }

  int b = bh >> 3, hh = bh & 7;
  int qr = lane >> 2, c0 = (lane & 3) * 16;
#pragma unroll
  for (int s = 0; s < 2; ++s) {
    float l = ls[s];
    l += __shfl_xor(l, 16);
    l += __shfl_xor(l, 32);
    float inv = 1.0f / l;
#pragma unroll
    for (int nt = 0; nt < 4; ++nt) {
      bf16x4 ov;
      ov[0] = (bf16)(Ot[s][nt][0] * inv); ov[1] = (bf16)(Ot[s][nt][1] * inv);
      ov[2] = (bf16)(Ot[s][nt][2] * inv); ov[3] = (bf16)(Ot[s][nt][3] * inv);
      *reinterpret_cast<bf16x4*>(&Pw[w][s][l15][nt * 16 + quad * 4]) = ov;
    }
    bf16x8 o0 = *reinterpret_cast<const bf16x8*>(&Pw[w][s][qr][c0]);
    bf16x8 o1 = *reinterpret_cast<const bf16x8*>(&Pw[w][s][qr][c0 + 8]);
    int token = b * SEQ + qt * 128 + s * 64 + w * 16 + qr;
    *reinterpret_cast<bf16x8*>(out + (size_t)token * DIMD + hh * DH + c0) = o0;
    *reinterpret_cast<bf16x8*>(out + (size_t)token * DIMD + hh * DH + c0 + 8) = o1;
  }
}

// ---------------- layernorm: bf16 in, bf16 out ----------------
__global__ void k_ln(const bf16* __restrict__ in, const float* __restrict__ g,
                     const float* __restrict__ b, bf16* __restrict__ outb) {
  int wid = (blockIdx.x * blockDim.x + threadIdx.x) >> 6;
  int lane = threadIdx.x & 63;
  bf16x8 xv = *reinterpret_cast<const bf16x8*>(in + (size_t)wid * DIMD + lane * 8);
  float xs[8];
  float s = 0.f, sq = 0.f;
#pragma unroll
  for (int j = 0; j < 8; ++j) { xs[j] = (float)xv[j]; s += xs[j]; sq += xs[j] * xs[j]; }
#pragma unroll
  for (int m = 1; m < 64; m <<= 1) { s += __shfl_xor(s, m); sq += __shfl_xor(sq, m); }
  float mu = s * (1.0f / DIMD);
  float var = sq * (1.0f / DIMD) - mu * mu;
  float rstd = rsqrtf(var + LNEPS);
  bf16x8 ov;
#pragma unroll
  for (int j = 0; j < 8; ++j) {
    int c = lane * 8 + j;
    ov[j] = (bf16)((xs[j] - mu) * rstd * g[c] + b[c]);
  }
  *reinterpret_cast<bf16x8*>(outb + (size_t)wid * DIMD + lane * 8) = ov;
}

// ---------------- classifier head ----------------
__global__ void k_head(const bf16* __restrict__ h, const float* __restrict__ w,
                       const float* __restrict__ bh, float* __restrict__ out) {
  int row = (blockIdx.x * blockDim.x + threadIdx.x) >> 6;
  int lane = threadIdx.x & 63;
  bf16x8 xv = *reinterpret_cast<const bf16x8*>(h + (size_t)row * DIMD + lane * 8);
  float s = 0.f;
#pragma unroll
  for (int j = 0; j < 8; ++j) s += (float)xv[j] * w[lane * 8 + j];
#pragma unroll
  for (int m = 1; m < 64; m <<= 1) s += __shfl_xor(s, m);
  if (lane == 0) out[row] = s + bh[0];
}

extern "C" void kernel_launch(void* const* d_in, const int* in_sizes, int n_in,
                              void* d_out, int out_size, void* d_ws, size_t ws_size,
                              hipStream_t stream) {
  const int*   x     = (const int*)d_in[0];
  const float* embed = (const float*)d_in[1];
  const float* pe    = (const float*)d_in[2];
  const float* Wqkv  = (const float*)d_in[3];
  const float* W0    = (const float*)d_in[4];
  const float* g1    = (const float*)d_in[5];
  const float* b1    = (const float*)d_in[6];
  const float* g2    = (const float*)d_in[7];
  const float* b2    = (const float*)d_in[8];
  const float* Wl1   = (const float*)d_in[9];
  const float* bl1   = (const float*)d_in[10];
  const float* Wl2   = (const float*)d_in[11];
  const float* bl2   = (const float*)d_in[12];
  const float* Whead = (const float*)d_in[13];
  const float* bhead = (const float*)d_in[14];
  float* outp = (float*)d_out;

  char* ws = (char*)d_ws;
  size_t off = 0;
  auto alloc = [&](size_t bytes) { void* p = ws + off; off += (bytes + 255) & ~(size_t)255; return p; };
  const size_t ACT = (size_t)NTOK * DIMD;
  bf16*  hb   = (bf16*)alloc(ACT * 2);
  bf16*  qb   = (bf16*)alloc(ACT * 2);
  bf16*  kb   = (bf16*)alloc(ACT * 2);
  bf16*  vtb  = (bf16*)alloc(ACT * 2);
  bf16*  ao   = (bf16*)alloc(ACT * 2);
  bf16*  rb   = (bf16*)alloc(ACT * 2);
  bf16*  yb   = (bf16*)alloc(ACT * 2);
  bf16*  wqkt = (bf16*)alloc((size_t)NBLK * DIMD * 3 * DIMD * 2);
  bf16*  w0t  = (bf16*)alloc((size_t)NBLK * DIMD * DIMD * 2);
  bf16*  wl1t = (bf16*)alloc((size_t)NBLK * DIMD * DFF * 2);
  bf16*  wl2t = (bf16*)alloc((size_t)NBLK * DFF * DIMD * 2);
  bf16*  mid  = qb;   // [NTOK][DFF] bf16 = 32 MB, aliases qb/kb/vtb/ao

  k_cvt_qkv<<<dim3(3 * DIMD / 32, DIMD / 32, NBLK), 256, 0, stream>>>(Wqkv, wqkt, DIMD, 3 * DIMD);
  k_cvt_t<<<dim3(DIMD / 32, DIMD / 32, NBLK), 256, 0, stream>>>(W0, w0t, DIMD, DIMD);
  k_cvt_t<<<dim3(DFF / 32, DIMD / 32, NBLK), 256, 0, stream>>>(Wl1, wl1t, DIMD, DFF);
  k_cvt_t<<<dim3(DIMD / 32, DFF / 32, NBLK), 256, 0, stream>>>(Wl2, wl2t, DFF, DIMD);

  k_embed<<<NTOK, 256, 0, stream>>>(x, embed, pe, hb);
  for (int i = 0; i < NBLK; ++i) {
    k_gemm<EPI_QKV, 128><<<dim3(3 * DIMD / 128, NTOK / 128), 256, 0, stream>>>(
        hb, wqkt + (size_t)i * DIMD * 3 * DIMD, nullptr, nullptr,
        qb, kb, vtb, 3 * DIMD, DIMD);
    k_attn<<<dim3(SEQ / 128, BATCH * HEADS), 256, 0, stream>>>(qb, kb, vtb, ao);
    k_gemm<EPI_RES, 64><<<dim3(DIMD / 128, NTOK / 64), 256, 0, stream>>>(
        ao, w0t + (size_t)i * DIMD * DIMD, nullptr, hb,
        rb, nullptr, nullptr, DIMD, DIMD);
    k_ln<<<NTOK / 4, 256, 0, stream>>>(rb, g1 + i * DIMD, b1 + i * DIMD, yb);
    k_gemm<EPI_GELU, 128><<<dim3(DFF / 128, NTOK / 128), 256, 0, stream>>>(
        yb, wl1t + (size_t)i * DIMD * DFF, bl1 + (size_t)i * DFF, nullptr,
        mid, nullptr, nullptr, DFF, DIMD);
    k_gemm<EPI_BIASRES, 64><<<dim3(DIMD / 128, NTOK / 64), 256, 0, stream>>>(
        mid, wl2t + (size_t)i * DFF * DIMD, bl2 + (size_t)i * DIMD, yb,
        rb, nullptr, nullptr, DIMD, DFF);
    k_ln<<<NTOK / 4, 256, 0, stream>>>(rb, g2 + i * DIMD, b2 + i * DIMD, hb);
  }
  k_head<<<NTOK / 4, 256, 0, stream>>>(hb, Whead, bhead, outp);
}